// Round 4
// baseline (18390.697 us; speedup 1.0000x reference)
//
#include <hip/hip_runtime.h>
#include <hip/hip_bf16.h>
#include <math.h>

// ---- problem constants ----
constexpr int NN   = 131072;   // total nodes (B*NPG)
constexpr int NE   = 262144;   // edges
constexpr int BG   = 256;      // graphs
constexpr int CH   = 32;       // graphs per chunk
constexpr int NCHUNK = BG/CH;  // 8
constexpr int NCN  = CH*512;   // nodes per chunk = 16384

typedef __bf16 bf16x8 __attribute__((ext_vector_type(8)));
typedef float  f32x4  __attribute__((ext_vector_type(4)));

__device__ inline float sigm(float x){ return 1.f/(1.f+__expf(-x)); }
__device__ inline float sigm2(float x){ return __builtin_amdgcn_rcpf(1.f + __expf(-x)); }
__device__ inline float blo(unsigned u){ union{unsigned a;float f;}v; v.a=u<<16; return v.f; }
__device__ inline float bhi(unsigned u){ union{unsigned a;float f;}v; v.a=u&0xffff0000u; return v.f; }
__device__ inline unsigned short f2bu(float f){
  union{float f;unsigned u;}v; v.f=f;
  unsigned u = v.u + 0x7fffu + ((v.u>>16)&1u);
  return (unsigned short)(u>>16);
}

__global__ void k_zero(int* __restrict__ p, int n){
  int i = blockIdx.x*256 + threadIdx.x;
  if (i < n) p[i] = 0;
}

// ---------------- node encoder ----------------
__global__ void k_node_enc(const int* __restrict__ x, const float* __restrict__ emb,
                           float* __restrict__ h0){
  int n = blockIdx.x*256 + threadIdx.x;
  if (n >= NN) return;
  int nt = x[2*n], ninv = x[2*n+1];
  float4 v; v.x = emb[nt*3+0]; v.y = emb[nt*3+1]; v.z = emb[nt*3+2]; v.w = (float)ninv;
  reinterpret_cast<float4*>(h0)[n] = v;
}

// ---------------- CSR build (by dst) ----------------
__global__ void k_count(const int* __restrict__ ei, int* __restrict__ deg){
  int e = blockIdx.x*256 + threadIdx.x;
  if (e >= NE) return;
  atomicAdd(&deg[ei[NE + e]], 1);
}
__global__ void k_blocksum(const int* __restrict__ deg, int* __restrict__ bsum){
  __shared__ int sd[256];
  int t = threadIdx.x;
  const int* p = deg + blockIdx.x*1024;
  int s = p[t*4] + p[t*4+1] + p[t*4+2] + p[t*4+3];
  sd[t]=s; __syncthreads();
  for (int d=128; d>0; d>>=1){ if (t<d) sd[t]+=sd[t+d]; __syncthreads(); }
  if (!t) bsum[blockIdx.x] = sd[0];
}
__global__ void k_scanbsum(const int* __restrict__ bsum, int* __restrict__ boff, int* __restrict__ offN){
  __shared__ int s[128];
  int t = threadIdx.x;           // 128 threads
  int mine = bsum[t];
  s[t]=mine; __syncthreads();
  for (int d=1; d<128; d<<=1){ int v = (t>=d)? s[t-d]:0; __syncthreads(); s[t]+=v; __syncthreads(); }
  boff[t] = s[t]-mine;
  if (t==127) offN[0] = s[127];
}
__global__ void k_scanchunk(const int* __restrict__ deg, const int* __restrict__ boff, int* __restrict__ offs){
  __shared__ int ts[256];
  int t = threadIdx.x, b = blockIdx.x;
  const int* p = deg + b*1024;
  int v0=p[t*4],v1=p[t*4+1],v2=p[t*4+2],v3=p[t*4+3];
  int mysum=v0+v1+v2+v3;
  ts[t]=mysum; __syncthreads();
  for (int d=1; d<256; d<<=1){ int v=(t>=d)?ts[t-d]:0; __syncthreads(); ts[t]+=v; __syncthreads(); }
  int ex = ts[t]-mysum + boff[b];
  int* o = offs + b*1024 + t*4;
  o[0]=ex; o[1]=ex+v0; o[2]=ex+v0+v1; o[3]=ex+v0+v1+v2;
}
__global__ void k_fill(const int* __restrict__ ei, const int* __restrict__ offs,
                       int* __restrict__ cur, int* __restrict__ esrc){
  int e = blockIdx.x*256 + threadIdx.x;
  if (e >= NE) return;
  int dst = ei[NE+e];
  int pos = offs[dst] + atomicAdd(&cur[dst],1);
  esrc[pos] = ei[e];
}

// ---------------- softmax aggregation, 4-channel (conv1) ----------------
__global__ void k_aggr4(const float* __restrict__ h, const int* __restrict__ offs,
                        const int* __restrict__ esrc, const float* __restrict__ tptr,
                        float* __restrict__ ag){
  int n = blockIdx.x*256 + threadIdx.x;
  if (n >= NN) return;
  int s = offs[n], e = offs[n+1];
  float4 z = {0,0,0,0};
  if (s == e){ reinterpret_cast<float4*>(ag)[n] = z; return; }
  float t = *tptr;
  float4 m = {-3e38f,-3e38f,-3e38f,-3e38f};
  for (int i=s;i<e;++i){
    float4 v = reinterpret_cast<const float4*>(h)[esrc[i]];
    m.x=fmaxf(m.x,v.x*t); m.y=fmaxf(m.y,v.y*t); m.z=fmaxf(m.z,v.z*t); m.w=fmaxf(m.w,v.w*t);
  }
  float4 num=z, den=z;
  for (int i=s;i<e;++i){
    float4 v = reinterpret_cast<const float4*>(h)[esrc[i]];
    float ex;
    ex=__expf(v.x*t-m.x); num.x+=v.x*ex; den.x+=ex;
    ex=__expf(v.y*t-m.y); num.y+=v.y*ex; den.y+=ex;
    ex=__expf(v.z*t-m.z); num.z+=v.z*ex; den.z+=ex;
    ex=__expf(v.w*t-m.w); num.w+=v.w*ex; den.w+=ex;
  }
  float4 r = {num.x/den.x, num.y/den.y, num.z/den.z, num.w/den.w};
  reinterpret_cast<float4*>(ag)[n] = r;
}

// ---------------- softmax aggregation, 256-channel, chunked ----------------
__global__ __launch_bounds__(256) void k_aggr256(const float* __restrict__ hloc, const int* __restrict__ offs,
                          const int* __restrict__ esrc, const float* __restrict__ tptr,
                          float* __restrict__ ag, int base){
  int n = base + blockIdx.x, c = threadIdx.x;
  int s = offs[n], e = offs[n+1];
  if (s == e){ ag[(size_t)blockIdx.x*256+c] = 0.f; return; }
  float t = *tptr;
  float m = -3e38f;
  for (int i=s;i<e;++i) m = fmaxf(m, hloc[(size_t)(esrc[i]-base)*256 + c]*t);
  float num=0.f, den=0.f;
  for (int i=s;i<e;++i){
    float v = hloc[(size_t)(esrc[i]-base)*256 + c];
    float ex = __expf(v*t - m);
    num += v*ex; den += ex;
  }
  ag[(size_t)blockIdx.x*256+c] = num/den;
}

// ---------------- conv1 linear (K=4, fused), chunked ----------------
__global__ __launch_bounds__(256) void k_conv1_lin(const float* __restrict__ ag, const float* __restrict__ h0,
                            const float* __restrict__ lW, const float* __restrict__ lb,
                            const float* __restrict__ rW, float* __restrict__ out, int base){
  int n = base + blockIdx.x, c = threadIdx.x;
  float4 a  = reinterpret_cast<const float4*>(ag)[n];
  float4 xv = reinterpret_cast<const float4*>(h0)[n];
  float acc = lb[c];
  acc += a.x*lW[c]  + a.y*lW[256+c]  + a.z*lW[512+c]  + a.w*lW[768+c];
  acc += xv.x*rW[c] + xv.y*rW[256+c] + xv.z*rW[512+c] + xv.w*rW[768+c];
  out[(size_t)blockIdx.x*256 + c] = fmaxf(acc, 0.f);
}

// ---------------- generic f32 GEMM, 128x128 tile, 8x8 microtile ----------------
#define GF_BIAS    1
#define GF_RELU    2
#define GF_RESID   4
#define GF_RESID_B 8
#define GF_ADDC    32
#define GF_ATOMIC  64
#define GF_BF16    128

template<int FLAGS>
__global__ __launch_bounds__(256) void k_gemm(const float* __restrict__ A, const float* __restrict__ Bm,
                       const float* __restrict__ bias, const float* __restrict__ resid,
                       float* __restrict__ C, int M, int Nn, int K){
  __shared__ float As[16][128];
  __shared__ float Bs[16][128];
  const int m0 = blockIdx.x*128, n0 = blockIdx.y*128;
  const int kChunk = K / gridDim.z;
  const int kBeg = blockIdx.z * kChunk;
  const int tid = threadIdx.x;
  const int tm = tid>>4, tn = tid&15;
  const int mA = tid>>2, kA = (tid&3)*4;
  const int kB = tid>>4, nB = (tid&15)*8;
  float acc[8][8] = {};
  for (int k0=kBeg; k0<kBeg+kChunk; k0+=16){
    float4 a0 = *reinterpret_cast<const float4*>(A + (size_t)(m0+mA)*K + k0 + kA);
    float4 a1 = *reinterpret_cast<const float4*>(A + (size_t)(m0+mA+64)*K + k0 + kA);
    float4 b0 = *reinterpret_cast<const float4*>(Bm + (size_t)(k0+kB)*Nn + n0 + nB);
    float4 b1 = *reinterpret_cast<const float4*>(Bm + (size_t)(k0+kB)*Nn + n0 + nB + 4);
    __syncthreads();    // previous tile consumed
    As[kA+0][mA]=a0.x; As[kA+1][mA]=a0.y; As[kA+2][mA]=a0.z; As[kA+3][mA]=a0.w;
    As[kA+0][mA+64]=a1.x; As[kA+1][mA+64]=a1.y; As[kA+2][mA+64]=a1.z; As[kA+3][mA+64]=a1.w;
    *reinterpret_cast<float4*>(&Bs[kB][nB])   = b0;
    *reinterpret_cast<float4*>(&Bs[kB][nB+4]) = b1;
    __syncthreads();    // tile ready
    #pragma unroll
    for (int kk=0;kk<16;++kk){
      float4 x0 = *reinterpret_cast<const float4*>(&As[kk][tm*8]);
      float4 x1 = *reinterpret_cast<const float4*>(&As[kk][tm*8+4]);
      float4 y0 = *reinterpret_cast<const float4*>(&Bs[kk][tn*8]);
      float4 y1 = *reinterpret_cast<const float4*>(&Bs[kk][tn*8+4]);
      float av[8]={x0.x,x0.y,x0.z,x0.w,x1.x,x1.y,x1.z,x1.w};
      float bv[8]={y0.x,y0.y,y0.z,y0.w,y1.x,y1.y,y1.z,y1.w};
      #pragma unroll
      for (int i=0;i<8;++i){
        #pragma unroll
        for (int j=0;j<8;++j) acc[i][j] += av[i]*bv[j];
      }
    }
  }
  #pragma unroll
  for (int i=0;i<8;++i){
    const size_t m = (size_t)m0 + tm*8 + i;
    #pragma unroll
    for (int j=0;j<8;++j){
      const int n = n0 + tn*8 + j;
      size_t idx = m*(size_t)Nn + n;
      float v = acc[i][j];
      if (FLAGS & GF_ATOMIC){ atomicAdd(&C[idx], v); }
      else {
        if (FLAGS & GF_BIAS)    v += bias[n];
        if (FLAGS & GF_ADDC)    v += C[idx];
        if (FLAGS & GF_RELU)    v = fmaxf(v, 0.f);
        if (FLAGS & GF_RESID)   v += resid[idx];
        if (FLAGS & GF_RESID_B) v += resid[n];
        if (FLAGS & GF_BF16) reinterpret_cast<__hip_bfloat16*>(C)[idx] = __float2bfloat16(v);
        else C[idx] = v;
      }
    }
  }
}

// ---------------- small utilities ----------------
__global__ void k_rowbias(const float* __restrict__ bias, float* __restrict__ C, int Nn, int total){
  int i = blockIdx.x*256 + threadIdx.x;
  if (i < total) C[i] = bias[i % Nn];
}
__global__ void k_qvec(const float* __restrict__ seed, const float* __restrict__ Wq,
                       const float* __restrict__ bq, float* __restrict__ qv){
  __shared__ float s[256];
  int t = threadIdx.x;
  s[t] = seed[t]; __syncthreads();
  float acc = bq[t];
  for (int c = 0; c < 256; ++c) acc += s[c] * Wq[c*256 + t];
  qv[t] = acc;
}
__global__ void k_concat(const float* __restrict__ p1, const float* __restrict__ p2,
                         const float* __restrict__ p3, float* __restrict__ pooled){
  int idx = blockIdx.x*256 + threadIdx.x;    // 256*768
  int b = idx / 768, j = idx % 768;
  float v = (j < 256) ? p1[b*256+j] : (j < 512) ? p2[b*256+j-256] : p3[b*256+j-512];
  pooled[idx] = v;
}

// ---------------- GRU weight pack: combined [512][1024] bf16, MFMA-fragment layout ----
// B[k][j]: k<256 -> x-part: j<768: Wih[j][k], else 0
//          k>=256 -> h-part: j<512: Whh[j][k-256]; 512<=j<768: 0; j>=768: Whh[512+(j-768)][k-256]
// packed: Bp[((k>>3)*1024 + j)*8 + (k&7)]
__global__ void k_packgru(const float* __restrict__ gWih, const float* __restrict__ gWhh,
                          const float* __restrict__ gbih, const float* __restrict__ gbhh,
                          ushort* __restrict__ Bp, float* __restrict__ bc){
  int idx = blockIdx.x*256 + threadIdx.x;     // 512*1024
  if (idx >= 524288) return;
  int k = idx >> 10, j = idx & 1023;
  float v = 0.f;
  if (k < 256){
    if (j < 768) v = gWih[j*256 + k];
  } else {
    int kp = k - 256;
    if (j < 512) v = gWhh[j*256 + kp];
    else if (j >= 768) v = gWhh[(512 + (j-768))*256 + kp];
  }
  Bp[ ((size_t)(k>>3)*1024 + j)*8 + (k&7) ] = f2bu(v);
  if (idx < 1024){
    int c = idx & 255;
    float b;
    if (idx < 256)      b = gbih[c] + gbhh[c];
    else if (idx < 512) b = gbih[256+c] + gbhh[256+c];
    else if (idx < 768) b = gbih[512+c];
    else                b = gbhh[512+c];
    bc[idx] = b;
  }
}

// ---------------- GRU v4: MFMA. 16 graphs/block, 16 blocks, 512 thr (8 waves) ----
// per step: gates[16][1024] = A[16][512] @ B[512][1024], A = [x_t | h_{t-1}] bf16
__device__ inline int gswz(int row, int j){ return row*1024 + (j ^ ((row&3)<<3)); }

__global__ __launch_bounds__(512) void k_gru4(const float* __restrict__ X,
                      const ushort* __restrict__ Bp, const float* __restrict__ bc,
                      float* __restrict__ p2){
  extern __shared__ char smem[];
  ushort* Ald = (ushort*)smem;            // [16 rows][64 16B-blocks], kb xor-swizzled (16KB)
  float*  G   = (float*)(smem + 16384);   // [16][1024] f32, col xor-swizzled (64KB)
  const int tid = threadIdx.x;
  const int g0 = blockIdx.x * 16;
  const int m  = tid >> 5, c8 = tid & 31;        // gate-phase ownership: graph m, cols c8*8..+8
  const int wv = tid >> 6, lane = tid & 63;      // MFMA decomposition
  const int arow = lane & 15, kg = lane >> 4;
  const int colb = wv*128 + arow;                // this lane's col for B/D
  float hreg[8];
  { // init: h=0 (regs + LDS), x0 -> LDS
    #pragma unroll
    for (int r=0;r<8;++r) hreg[r]=0.f;
    uint4 z = {0,0,0,0};
    *reinterpret_cast<uint4*>(&Ald[((size_t)m*64 + ((32+c8) ^ (m&7)))*8]) = z;
    const float4* xp = reinterpret_cast<const float4*>(X + ((size_t)(g0+m)*512)*256 + c8*8);
    float4 xa = xp[0], xb = xp[1];
    ushort xs[8] = {f2bu(xa.x),f2bu(xa.y),f2bu(xa.z),f2bu(xa.w),f2bu(xb.x),f2bu(xb.y),f2bu(xb.z),f2bu(xb.w)};
    *reinterpret_cast<uint4*>(&Ald[((size_t)m*64 + (c8 ^ (m&7)))*8]) = *reinterpret_cast<uint4*>(xs);
  }
  for (int t=0; t<512; ++t){
    __syncthreads();                             // A ready
    f32x4 acc[8] = {};
    #pragma unroll
    for (int kk=0; kk<16; ++kk){
      const int kb = kk*4 + kg;
      bf16x8 af = *reinterpret_cast<const bf16x8*>(&Ald[(arow*64 + (kb ^ (arow&7)))*8]);
      const ushort* bp = Bp + ((size_t)kb*1024 + colb)*8;
      #pragma unroll
      for (int tt=0; tt<8; ++tt){
        bf16x8 bfr = *reinterpret_cast<const bf16x8*>(bp + tt*128);
        acc[tt] = __builtin_amdgcn_mfma_f32_16x16x32_bf16(af, bfr, acc[tt], 0, 0, 0);
      }
    }
    // D -> G : lane holds D[row=kg*4+r][col = wv*128 + tt*16 + arow]
    #pragma unroll
    for (int tt=0; tt<8; ++tt){
      const int jc = wv*128 + tt*16 + arow;
      #pragma unroll
      for (int r=0;r<4;++r) G[gswz(kg*4+r, jc)] = acc[tt][r];
    }
    __syncthreads();                             // gates ready
    float4 xa, xb;
    const bool last = (t==511);
    if (!last){
      const float4* xp = reinterpret_cast<const float4*>(X + ((size_t)(g0+m)*512 + t+1)*256 + c8*8);
      xa = xp[0]; xb = xp[1];
    }
    const int j0 = c8*8;
    float4 ra = *reinterpret_cast<const float4*>(&G[gswz(m, j0)]);
    float4 rb = *reinterpret_cast<const float4*>(&G[gswz(m, j0)] + 4);
    float4 za = *reinterpret_cast<const float4*>(&G[gswz(m, 256+j0)]);
    float4 zb = *reinterpret_cast<const float4*>(&G[gswz(m, 256+j0)] + 4);
    float4 ia = *reinterpret_cast<const float4*>(&G[gswz(m, 512+j0)]);
    float4 ib = *reinterpret_cast<const float4*>(&G[gswz(m, 512+j0)] + 4);
    float4 ha = *reinterpret_cast<const float4*>(&G[gswz(m, 768+j0)]);
    float4 hb = *reinterpret_cast<const float4*>(&G[gswz(m, 768+j0)] + 4);
    float grs[8]={ra.x,ra.y,ra.z,ra.w,rb.x,rb.y,rb.z,rb.w};
    float gzs[8]={za.x,za.y,za.z,za.w,zb.x,zb.y,zb.z,zb.w};
    float gis[8]={ia.x,ia.y,ia.z,ia.w,ib.x,ib.y,ib.z,ib.w};
    float ghs[8]={ha.x,ha.y,ha.z,ha.w,hb.x,hb.y,hb.z,hb.w};
    ushort hs[8];
    #pragma unroll
    for (int r=0;r<8;++r){
      const int c = j0 + r;
      float rr = sigm2(grs[r] + bc[c]);
      float zz = sigm2(gzs[r] + bc[256+c]);
      float nx = gis[r] + bc[512+c] + rr*(ghs[r] + bc[768+c]);
      nx = fminf(fmaxf(nx, -15.f), 15.f);
      float e2 = __expf(2.f*nx);
      float nn = (e2-1.f)*__builtin_amdgcn_rcpf(e2+1.f);
      float hv = zz*hreg[r] + (1.f-zz)*nn;
      hreg[r] = hv;
      hs[r] = f2bu(hv);
    }
    if (!last){
      ushort xs[8] = {f2bu(xa.x),f2bu(xa.y),f2bu(xa.z),f2bu(xa.w),f2bu(xb.x),f2bu(xb.y),f2bu(xb.z),f2bu(xb.w)};
      *reinterpret_cast<uint4*>(&Ald[(m*64 + ((32+c8) ^ (m&7)))*8]) = *reinterpret_cast<uint4*>(hs);
      *reinterpret_cast<uint4*>(&Ald[(m*64 + (c8 ^ (m&7)))*8])      = *reinterpret_cast<uint4*>(xs);
    }
  }
  #pragma unroll
  for (int r=0;r<8;++r) p2[(size_t)(g0+m)*256 + c8*8 + r] = hreg[r];
}

// ---------------- fused SAB attention, bf16 K/V: per (graph-in-chunk, 8 q-rows) ----
__global__ __launch_bounds__(256) void k_attn(float* __restrict__ Q, const __hip_bfloat16* __restrict__ K,
                       const __hip_bfloat16* __restrict__ V){
  __shared__ float Qs[8*256];        // 8KB
  __shared__ float S [8*512];        // 16KB
  __shared__ uint4 Ks[32*32];        // 16KB (xor-swizzled, 8 bf16 per uint4)
  const int g = blockIdx.y, q0 = blockIdx.x*8, tid = threadIdx.x;
  const size_t gb = (size_t)g*512*256;
  for (int i=tid;i<2048;i+=256) Qs[i] = Q[gb + (size_t)q0*256 + i];
  const int q = tid>>5, kl = tid&31;
  const float* qp = Qs + q*256;
  float* Sq = S + q*512;
  for (int kt=0; kt<512; kt+=32){
    __syncthreads();
    for (int i=tid;i<1024;i+=256){
      int row = i>>5, c8 = i&31;
      Ks[row*32 + (c8^row)] =
        reinterpret_cast<const uint4*>(K + gb + (size_t)(kt+row)*256)[c8];
    }
    __syncthreads();
    float d = 0.f;
    #pragma unroll
    for (int c8=0;c8<32;++c8){
      uint4 kv = Ks[kl*32 + (c8^kl)];
      const float* qq = qp + c8*8;
      d += qq[0]*blo(kv.x) + qq[1]*bhi(kv.x) + qq[2]*blo(kv.y) + qq[3]*bhi(kv.y)
         + qq[4]*blo(kv.z) + qq[5]*bhi(kv.z) + qq[6]*blo(kv.w) + qq[7]*bhi(kv.w);
    }
    Sq[kt+kl] = d;
  }
  __syncthreads();
  // softmax over 512 raw dots of row q (scale 1/16)
  float m = -3e38f;
  for (int j=kl;j<512;j+=32) m = fmaxf(m, Sq[j]);
  #pragma unroll
  for (int o=1;o<32;o<<=1) m = fmaxf(m, __shfl_xor(m,o));
  float sum = 0.f;
  for (int j=kl;j<512;j+=32){ float e = __expf((Sq[j]-m)*0.0625f); Sq[j]=e; sum+=e; }
  #pragma unroll
  for (int o=1;o<32;o<<=1) sum += __shfl_xor(sum,o);
  const float inv = 1.f/sum;
  __syncthreads();
  // AV: thread owns (q, 8 channels)
  const int c0 = kl*8;
  float a0=0,a1=0,a2=0,a3=0,a4=0,a5=0,a6=0,a7=0;
  for (int k=0;k<512;++k){
    float a = Sq[k];
    uint4 vv = *reinterpret_cast<const uint4*>(V + gb + (size_t)k*256 + c0);
    a0+=a*blo(vv.x); a1+=a*bhi(vv.x); a2+=a*blo(vv.y); a3+=a*bhi(vv.y);
    a4+=a*blo(vv.z); a5+=a*bhi(vv.z); a6+=a*blo(vv.w); a7+=a*bhi(vv.w);
  }
  float* op = Q + gb + (size_t)(q0+q)*256 + c0;   // overwrite own Q rows with AV
  float4 o0 = {a0*inv,a1*inv,a2*inv,a3*inv};
  float4 o1 = {a4*inv,a5*inv,a6*inv,a7*inv};
  *reinterpret_cast<float4*>(op)   = o0;
  *reinterpret_cast<float4*>(op+4) = o1;
}

// ---------------- PMA attention (1 query per graph), chunked ----------------
__global__ __launch_bounds__(256) void k_attn2(const float* __restrict__ K2, const float* __restrict__ V2,
                        const float* __restrict__ qv, float* __restrict__ av2){
  int g = blockIdx.x, tid = threadIdx.x;
  __shared__ float qs[256];
  __shared__ float sc[512];
  __shared__ float red[4];
  qs[tid] = qv[tid];
  __syncthreads();
  const size_t gb = (size_t)g*512*256;
  float l0=0.f, l1=0.f;
  for (int j0=0;j0<2;++j0){
    int j = tid + j0*256;
    const float* kr = K2 + gb + (size_t)j*256;
    float a = 0.f;
    for (int c=0;c<256;c+=4){
      float4 k4 = *reinterpret_cast<const float4*>(kr + c);
      a += k4.x*qs[c] + k4.y*qs[c+1] + k4.z*qs[c+2] + k4.w*qs[c+3];
    }
    a *= 0.0625f;
    if (j0) l1=a; else l0=a;
  }
  float m = fmaxf(l0,l1);
  #pragma unroll
  for (int o=1;o<64;o<<=1) m = fmaxf(m, __shfl_xor(m,o));
  if ((tid&63)==0) red[tid>>6] = m;
  __syncthreads();
  m = fmaxf(fmaxf(red[0],red[1]), fmaxf(red[2],red[3]));
  __syncthreads();
  float e0 = __expf(l0-m), e1 = __expf(l1-m);
  sc[tid]=e0; sc[tid+256]=e1;
  float s = e0+e1;
  #pragma unroll
  for (int o=1;o<64;o<<=1) s += __shfl_xor(s,o);
  if ((tid&63)==0) red[tid>>6] = s;
  __syncthreads();
  s = red[0]+red[1]+red[2]+red[3];
  float invs = 1.f/s;
  float acc = 0.f;
  for (int j=0;j<512;++j) acc += sc[j] * V2[gb + (size_t)j*256 + tid];
  av2[(size_t)g*256+tid] = acc*invs;
}

// =====================================================================
extern "C" void kernel_launch(void* const* d_in, const int* in_sizes, int n_in,
                              void* d_out, int out_size, void* d_ws, size_t ws_size,
                              hipStream_t stream){
  const int*   x      = (const int*)  d_in[0];
  const int*   ei     = (const int*)  d_in[1];
  const float* emb_w  = (const float*)d_in[3];
  const float* c1_lW  = (const float*)d_in[4];
  const float* c1_lb  = (const float*)d_in[5];
  const float* c1_rW  = (const float*)d_in[6];
  const float* t1     = (const float*)d_in[7];
  const float* c2_lW  = (const float*)d_in[8];
  const float* c2_lb  = (const float*)d_in[9];
  const float* c2_rW  = (const float*)d_in[10];
  const float* t2     = (const float*)d_in[11];
  const float* mlp_W  = (const float*)d_in[12];
  const float* mlp_b  = (const float*)d_in[13];
  const float* gWih   = (const float*)d_in[14];
  const float* gWhh   = (const float*)d_in[15];
  const float* gbih   = (const float*)d_in[16];
  const float* gbhh   = (const float*)d_in[17];
  const float* stWq   = (const float*)d_in[18];
  const float* stbq   = (const float*)d_in[19];
  const float* stWk   = (const float*)d_in[20];
  const float* stbk   = (const float*)d_in[21];
  const float* stWv   = (const float*)d_in[22];
  const float* stbv   = (const float*)d_in[23];
  const float* stWo   = (const float*)d_in[24];
  const float* stbo   = (const float*)d_in[25];
  const float* stlW   = (const float*)d_in[26];
  const float* stlb   = (const float*)d_in[27];
  const float* pma_lW = (const float*)d_in[28];
  const float* pma_lb = (const float*)d_in[29];
  const float* seed   = (const float*)d_in[30];
  const float* fin_W  = (const float*)d_in[31];
  const float* fin_b  = (const float*)d_in[32];
  float* out = (float*)d_out;

  // ---- workspace carve (peak ~196 MB, same layout as round 3) ----
  float* H2   = (float*)d_ws;                    // 33,554,432 (NN x 256, persists)
  float* bufA = H2   + (size_t)33554432;         // 4,194,304  (chunk buf)
  float* bufB = bufA + (size_t)4194304;
  float* bufC = bufB + (size_t)4194304;
  float* h0   = bufC + (size_t)4194304;          // NN*4
  float* ag1  = h0   + (size_t)524288;           // NN*4
  float* wT1  = ag1  + (size_t)524288;           // 393216 floats total (wT1+wT2): GRU pack area
  float* wT2  = wT1  + (size_t)196608;
  float* p1   = wT2  + (size_t)196608;           // 256*256
  float* p2   = p1   + (size_t)65536;
  float* p3   = p2   + (size_t)65536;
  float* av2  = p3   + (size_t)65536;
  float* s1   = av2  + (size_t)65536;
  float* s2v  = s1   + (size_t)65536;
  float* v3   = s2v  + (size_t)65536;
  float* h3   = v3   + (size_t)65536;
  float* pooled = h3 + (size_t)65536;            // 256*768
  float* qv   = pooled + (size_t)196608;         // 256 (+pad)
  int*   deg  = (int*)(qv + 320);                // NN
  int*   offs = deg  + 131072;                   // NN + pad (offs[NN] used)
  int*   cur  = offs + 131200;                   // NN
  int*   esrc = cur  + 131072;                   // NE
  int*   bsum = esrc + 262144;                   // 128
  int*   boff = bsum + 128;                      // 128
  size_t need = ((size_t)((boff + 128) - (int*)d_ws))*4 + 4096;
  if (ws_size < need) return;   // diagnostic: clean absmax failure instead of OOB hang

  ushort* gruB  = (ushort*)wT1;                  // 524288 ushort = 262144 floats
  float*  bcomb = wT1 + 262144 + 64;             // 1024 floats (inside wT1+wT2 area)

  const int ls0 = 65536, ls1 = 256;              // set-transformer layer strides

  // ---- 1. node encoder ----
  k_node_enc<<<NN/256, 256, 0, stream>>>(x, emb_w, h0);

  // ---- 2. CSR ----
  k_zero<<<NN/256, 256, 0, stream>>>(deg, NN);
  k_count<<<NE/256, 256, 0, stream>>>(ei, deg);
  k_blocksum<<<128, 256, 0, stream>>>(deg, bsum);
  k_scanbsum<<<1, 128, 0, stream>>>(bsum, boff, offs + NN);
  k_scanchunk<<<128, 256, 0, stream>>>(deg, boff, offs);
  k_zero<<<NN/256, 256, 0, stream>>>(cur, NN);
  k_fill<<<NE/256, 256, 0, stream>>>(ei, offs, cur, esrc);

  // ---- 3. conv1 aggregation (full batch, tiny: NN x 4) ----
  k_aggr4<<<NN/256, 256, 0, stream>>>(h0, offs, esrc, t1, ag1);

  // ---- 4. conv1 + conv2, chunked over 32-graph groups ----
  for (int cg = 0; cg < NCHUNK; ++cg){
    const int base = cg * NCN;
    float* Hc = H2 + (size_t)base * 256;
    k_conv1_lin<<<NCN, 256, 0, stream>>>(ag1, h0, c1_lW, c1_lb, c1_rW, bufA, base);   // h1_c
    k_aggr256<<<NCN, 256, 0, stream>>>(bufA, offs, esrc, t2, bufB, base);             // ag2_c
    k_gemm<0><<<dim3(NCN/128, 2, 1), 256, 0, stream>>>(bufB, c2_lW, nullptr, nullptr, Hc, NCN, 256, 256);
    k_gemm<GF_BIAS|GF_ADDC|GF_RELU><<<dim3(NCN/128, 2, 1), 256, 0, stream>>>(bufA, c2_rW, c2_lb, nullptr, Hc, NCN, 256, 256);
  }
  // H2 = h2 (full)

  // ---- 5. p1 = MLP pool (M=256, K=131072, split-K atomic) ----
  k_rowbias<<<256, 256, 0, stream>>>(mlp_b, p1, 256, 65536);
  k_gemm<GF_ATOMIC><<<dim3(2, 2, 64), 256, 0, stream>>>(H2, mlp_W, nullptr, nullptr, p1, 256, 256, NN);

  // ---- 6. GRU (MFMA, 16 graphs/block, 16 blocks) ----
  k_packgru<<<2048, 256, 0, stream>>>(gWih, gWhh, gbih, gbhh, gruB, bcomb);
  k_gru4<<<16, 512, 81920, stream>>>(H2, gruB, bcomb, p2);

  // ---- 7. set transformer, chunked over 32-graph groups ----
  k_qvec<<<1, 256, 0, stream>>>(seed, stWq + ls0, stbq + ls1, qv);
  for (int cg = 0; cg < NCHUNK; ++cg){
    const int base = cg * NCN;
    float* Hc = H2 + (size_t)base * 256;
    const dim3 gg(NCN/128, 2, 1);
    k_gemm<GF_BIAS><<<gg, 256, 0, stream>>>(Hc, stWq, stbq, nullptr, bufA, NCN, 256, 256);           // Q (f32)
    k_gemm<GF_BIAS|GF_BF16><<<gg, 256, 0, stream>>>(Hc, stWk, stbk, nullptr, bufB, NCN, 256, 256);   // K (bf16)
    k_gemm<GF_BIAS|GF_BF16><<<gg, 256, 0, stream>>>(Hc, stWv, stbv, nullptr, bufC, NCN, 256, 256);   // V (bf16)
    k_attn<<<dim3(64, CH), 256, 0, stream>>>(bufA, (const __hip_bfloat16*)bufB, (const __hip_bfloat16*)bufC); // AV -> bufA
    k_gemm<GF_BIAS|GF_RESID><<<gg, 256, 0, stream>>>(bufA, stWo, stbo, Hc, Hc, NCN, 256, 256);       // h_sab (in-place over h2)
    k_gemm<GF_BIAS|GF_RELU|GF_RESID><<<gg, 256, 0, stream>>>(Hc, stlW, stlb, Hc, bufA, NCN, 256, 256); // h_enc
    k_gemm<GF_BIAS|GF_RELU><<<gg, 256, 0, stream>>>(bufA, pma_lW, pma_lb, nullptr, bufB, NCN, 256, 256); // kk
    k_gemm<GF_BIAS><<<gg, 256, 0, stream>>>(bufB, stWk + ls0, stbk + ls1, nullptr, bufA, NCN, 256, 256); // K2 (f32)
    k_gemm<GF_BIAS><<<gg, 256, 0, stream>>>(bufB, stWv + ls0, stbv + ls1, nullptr, bufC, NCN, 256, 256); // V2 (f32)
    k_attn2<<<CH, 256, 0, stream>>>(bufA, bufC, qv, av2 + (size_t)cg*CH*256);
  }

  // ---- 8. PMA tail + decoder SAB (small, full batch) ----
  k_gemm<GF_BIAS|GF_RESID_B><<<dim3(2, 2, 1), 256, 0, stream>>>(av2, stWo + ls0, stbo + ls1, seed, s1, 256, 256, 256);
  k_gemm<GF_BIAS|GF_RELU|GF_RESID><<<dim3(2, 2, 1), 256, 0, stream>>>(s1, stlW + ls0, stlb + ls1, s1, s2v, 256, 256, 256);
  k_gemm<GF_BIAS><<<dim3(2, 2, 1), 256, 0, stream>>>(s2v, stWv + 2*ls0, stbv + 2*ls1, nullptr, v3, 256, 256, 256);
  k_gemm<GF_BIAS|GF_RESID><<<dim3(2, 2, 1), 256, 0, stream>>>(v3, stWo + 2*ls0, stbo + 2*ls1, s2v, h3, 256, 256, 256);
  k_gemm<GF_BIAS|GF_RELU|GF_RESID><<<dim3(2, 2, 1), 256, 0, stream>>>(h3, stlW + 2*ls0, stlb + 2*ls1, h3, p3, 256, 256, 256);

  // ---- 9. concat + final linear ----
  k_concat<<<768, 256, 0, stream>>>(p1, p2, p3, pooled);
  k_gemm<GF_BIAS><<<dim3(2, 6, 1), 256, 0, stream>>>(pooled, fin_W, fin_b, nullptr, out, 256, 768, 768);
}

// Round 5
// 5945.676 us; speedup vs baseline: 3.0931x; 3.0931x over previous
//
#include <hip/hip_runtime.h>
#include <hip/hip_bf16.h>
#include <math.h>

// ---- problem constants ----
constexpr int NN   = 131072;   // total nodes (B*NPG)
constexpr int NE   = 262144;   // edges
constexpr int BG   = 256;      // graphs

typedef __bf16 bf16x8 __attribute__((ext_vector_type(8)));
typedef float  f32x4  __attribute__((ext_vector_type(4)));

__device__ inline float sigm(float x){ return 1.f/(1.f+__expf(-x)); }
__device__ inline float blo(unsigned u){ union{unsigned a;float f;}v; v.a=u<<16; return v.f; }
__device__ inline float bhi(unsigned u){ union{unsigned a;float f;}v; v.a=u&0xffff0000u; return v.f; }
__device__ inline unsigned short f2bu(float f){
  union{float f;unsigned u;}v; v.f=f;
  unsigned u = v.u + 0x7fffu + ((v.u>>16)&1u);
  return (unsigned short)(u>>16);
}
__device__ inline bf16x8 cvt8(float4 a, float4 b){
  union { ushort u[8]; bf16x8 v; } r;
  r.u[0]=f2bu(a.x); r.u[1]=f2bu(a.y); r.u[2]=f2bu(a.z); r.u[3]=f2bu(a.w);
  r.u[4]=f2bu(b.x); r.u[5]=f2bu(b.y); r.u[6]=f2bu(b.z); r.u[7]=f2bu(b.w);
  return r.v;
}

__global__ void k_zero(int* __restrict__ p, int n){
  int i = blockIdx.x*256 + threadIdx.x;
  if (i < n) p[i] = 0;
}

// ---------------- node encoder ----------------
__global__ void k_node_enc(const int* __restrict__ x, const float* __restrict__ emb,
                           float* __restrict__ h0){
  int n = blockIdx.x*256 + threadIdx.x;
  if (n >= NN) return;
  int nt = x[2*n], ninv = x[2*n+1];
  float4 v; v.x = emb[nt*3+0]; v.y = emb[nt*3+1]; v.z = emb[nt*3+2]; v.w = (float)ninv;
  reinterpret_cast<float4*>(h0)[n] = v;
}

// ---------------- CSR build (by dst) ----------------
__global__ void k_count(const int* __restrict__ ei, int* __restrict__ deg){
  int e = blockIdx.x*256 + threadIdx.x;
  if (e >= NE) return;
  atomicAdd(&deg[ei[NE + e]], 1);
}
__global__ void k_blocksum(const int* __restrict__ deg, int* __restrict__ bsum){
  __shared__ int sd[256];
  int t = threadIdx.x;
  const int* p = deg + blockIdx.x*1024;
  int s = p[t*4] + p[t*4+1] + p[t*4+2] + p[t*4+3];
  sd[t]=s; __syncthreads();
  for (int d=128; d>0; d>>=1){ if (t<d) sd[t]+=sd[t+d]; __syncthreads(); }
  if (!t) bsum[blockIdx.x] = sd[0];
}
__global__ void k_scanbsum(const int* __restrict__ bsum, int* __restrict__ boff, int* __restrict__ offN){
  __shared__ int s[128];
  int t = threadIdx.x;
  int mine = bsum[t];
  s[t]=mine; __syncthreads();
  for (int d=1; d<128; d<<=1){ int v = (t>=d)? s[t-d]:0; __syncthreads(); s[t]+=v; __syncthreads(); }
  boff[t] = s[t]-mine;
  if (t==127) offN[0] = s[127];
}
__global__ void k_scanchunk(const int* __restrict__ deg, const int* __restrict__ boff, int* __restrict__ offs){
  __shared__ int ts[256];
  int t = threadIdx.x, b = blockIdx.x;
  const int* p = deg + b*1024;
  int v0=p[t*4],v1=p[t*4+1],v2=p[t*4+2],v3=p[t*4+3];
  int mysum=v0+v1+v2+v3;
  ts[t]=mysum; __syncthreads();
  for (int d=1; d<256; d<<=1){ int v=(t>=d)?ts[t-d]:0; __syncthreads(); ts[t]+=v; __syncthreads(); }
  int ex = ts[t]-mysum + boff[b];
  int* o = offs + b*1024 + t*4;
  o[0]=ex; o[1]=ex+v0; o[2]=ex+v0+v1; o[3]=ex+v0+v1+v2;
}
__global__ void k_fill(const int* __restrict__ ei, const int* __restrict__ offs,
                       int* __restrict__ cur, int* __restrict__ esrc){
  int e = blockIdx.x*256 + threadIdx.x;
  if (e >= NE) return;
  int dst = ei[NE+e];
  int pos = offs[dst] + atomicAdd(&cur[dst],1);
  esrc[pos] = ei[e];
}

// ---------------- softmax aggregation, 4-channel (conv1) ----------------
__global__ void k_aggr4(const float* __restrict__ h, const int* __restrict__ offs,
                        const int* __restrict__ esrc, const float* __restrict__ tptr,
                        float* __restrict__ ag){
  int n = blockIdx.x*256 + threadIdx.x;
  if (n >= NN) return;
  int s = offs[n], e = offs[n+1];
  float4 z = {0,0,0,0};
  if (s == e){ reinterpret_cast<float4*>(ag)[n] = z; return; }
  float t = *tptr;
  float4 m = {-3e38f,-3e38f,-3e38f,-3e38f};
  for (int i=s;i<e;++i){
    float4 v = reinterpret_cast<const float4*>(h)[esrc[i]];
    m.x=fmaxf(m.x,v.x*t); m.y=fmaxf(m.y,v.y*t); m.z=fmaxf(m.z,v.z*t); m.w=fmaxf(m.w,v.w*t);
  }
  float4 num=z, den=z;
  for (int i=s;i<e;++i){
    float4 v = reinterpret_cast<const float4*>(h)[esrc[i]];
    float ex;
    ex=__expf(v.x*t-m.x); num.x+=v.x*ex; den.x+=ex;
    ex=__expf(v.y*t-m.y); num.y+=v.y*ex; den.y+=ex;
    ex=__expf(v.z*t-m.z); num.z+=v.z*ex; den.z+=ex;
    ex=__expf(v.w*t-m.w); num.w+=v.w*ex; den.w+=ex;
  }
  float4 r = {num.x/den.x, num.y/den.y, num.z/den.z, num.w/den.w};
  reinterpret_cast<float4*>(ag)[n] = r;
}

// ---------------- softmax aggregation, 256-channel, chunked ----------------
__global__ __launch_bounds__(256) void k_aggr256(const float* __restrict__ hloc, const int* __restrict__ offs,
                          const int* __restrict__ esrc, const float* __restrict__ tptr,
                          float* __restrict__ ag, int base){
  int n = base + blockIdx.x, c = threadIdx.x;
  int s = offs[n], e = offs[n+1];
  if (s == e){ ag[(size_t)blockIdx.x*256+c] = 0.f; return; }
  float t = *tptr;
  float m = -3e38f;
  for (int i=s;i<e;++i) m = fmaxf(m, hloc[(size_t)(esrc[i]-base)*256 + c]*t);
  float num=0.f, den=0.f;
  for (int i=s;i<e;++i){
    float v = hloc[(size_t)(esrc[i]-base)*256 + c];
    float ex = __expf(v*t - m);
    num += v*ex; den += ex;
  }
  ag[(size_t)blockIdx.x*256+c] = num/den;
}

// ---------------- conv1 linear (K=4, fused), chunked ----------------
__global__ __launch_bounds__(256) void k_conv1_lin(const float* __restrict__ ag, const float* __restrict__ h0,
                            const float* __restrict__ lW, const float* __restrict__ lb,
                            const float* __restrict__ rW, float* __restrict__ out, int base){
  int n = base + blockIdx.x, c = threadIdx.x;
  float4 a  = reinterpret_cast<const float4*>(ag)[n];
  float4 xv = reinterpret_cast<const float4*>(h0)[n];
  float acc = lb[c];
  acc += a.x*lW[c]  + a.y*lW[256+c]  + a.z*lW[512+c]  + a.w*lW[768+c];
  acc += xv.x*rW[c] + xv.y*rW[256+c] + xv.z*rW[512+c] + xv.w*rW[768+c];
  out[(size_t)blockIdx.x*256 + c] = fmaxf(acc, 0.f);
}

// ---------------- flags ----------------
#define GF_BIAS    1
#define GF_RELU    2
#define GF_RESID   4
#define GF_RESID_B 8
#define GF_ADDC    32
#define GF_ATOMIC  64
#define GF_BF16    128

// ---------------- old f32 GEMM (kept for MLP-pool split-K atomic) ----------------
template<int FLAGS>
__global__ __launch_bounds__(256) void k_gemm(const float* __restrict__ A, const float* __restrict__ Bm,
                       const float* __restrict__ bias, const float* __restrict__ resid,
                       float* __restrict__ C, int M, int Nn, int K){
  __shared__ float As[16][128];
  __shared__ float Bs[16][128];
  const int m0 = blockIdx.x*128, n0 = blockIdx.y*128;
  const int kChunk = K / gridDim.z;
  const int kBeg = blockIdx.z * kChunk;
  const int tid = threadIdx.x;
  const int tm = tid>>4, tn = tid&15;
  const int mA = tid>>2, kA = (tid&3)*4;
  const int kB = tid>>4, nB = (tid&15)*8;
  float acc[8][8] = {};
  for (int k0=kBeg; k0<kBeg+kChunk; k0+=16){
    float4 a0 = *reinterpret_cast<const float4*>(A + (size_t)(m0+mA)*K + k0 + kA);
    float4 a1 = *reinterpret_cast<const float4*>(A + (size_t)(m0+mA+64)*K + k0 + kA);
    float4 b0 = *reinterpret_cast<const float4*>(Bm + (size_t)(k0+kB)*Nn + n0 + nB);
    float4 b1 = *reinterpret_cast<const float4*>(Bm + (size_t)(k0+kB)*Nn + n0 + nB + 4);
    __syncthreads();
    As[kA+0][mA]=a0.x; As[kA+1][mA]=a0.y; As[kA+2][mA]=a0.z; As[kA+3][mA]=a0.w;
    As[kA+0][mA+64]=a1.x; As[kA+1][mA+64]=a1.y; As[kA+2][mA+64]=a1.z; As[kA+3][mA+64]=a1.w;
    *reinterpret_cast<float4*>(&Bs[kB][nB])   = b0;
    *reinterpret_cast<float4*>(&Bs[kB][nB+4]) = b1;
    __syncthreads();
    #pragma unroll
    for (int kk=0;kk<16;++kk){
      float4 x0 = *reinterpret_cast<const float4*>(&As[kk][tm*8]);
      float4 x1 = *reinterpret_cast<const float4*>(&As[kk][tm*8+4]);
      float4 y0 = *reinterpret_cast<const float4*>(&Bs[kk][tn*8]);
      float4 y1 = *reinterpret_cast<const float4*>(&Bs[kk][tn*8+4]);
      float av[8]={x0.x,x0.y,x0.z,x0.w,x1.x,x1.y,x1.z,x1.w};
      float bv[8]={y0.x,y0.y,y0.z,y0.w,y1.x,y1.y,y1.z,y1.w};
      #pragma unroll
      for (int i=0;i<8;++i){
        #pragma unroll
        for (int j=0;j<8;++j) acc[i][j] += av[i]*bv[j];
      }
    }
  }
  #pragma unroll
  for (int i=0;i<8;++i){
    const size_t m = (size_t)m0 + tm*8 + i;
    #pragma unroll
    for (int j=0;j<8;++j){
      const int n = n0 + tn*8 + j;
      size_t idx = m*(size_t)Nn + n;
      float v = acc[i][j];
      if (FLAGS & GF_ATOMIC){ atomicAdd(&C[idx], v); }
      else {
        if (FLAGS & GF_BIAS)    v += bias[n];
        if (FLAGS & GF_ADDC)    v += C[idx];
        if (FLAGS & GF_RELU)    v = fmaxf(v, 0.f);
        if (FLAGS & GF_RESID)   v += resid[idx];
        if (FLAGS & GF_RESID_B) v += resid[n];
        if (FLAGS & GF_BF16) reinterpret_cast<__hip_bfloat16*>(C)[idx] = __float2bfloat16(v);
        else C[idx] = v;
      }
    }
  }
}

// ---------------- weight pack: f32 W[K][N] -> MFMA-B bf16 Bp[((k>>3)*N + j)*8 + (k&7)] ----
__global__ void k_packb(const float* __restrict__ W, ushort* __restrict__ Bp, int K, int N){
  int idx = blockIdx.x*256 + threadIdx.x;
  if (idx >= K*N) return;
  int k = idx / N, j = idx - k*N;
  Bp[((size_t)(k>>3)*N + j)*8 + (k&7)] = f2bu(W[idx]);
}
// transposed source: W is [N][K] row-major; B[k][j] = W[j][k]
__global__ void k_packbT(const float* __restrict__ W, ushort* __restrict__ Bp, int K, int N){
  int idx = blockIdx.x*256 + threadIdx.x;
  if (idx >= K*N) return;
  int j = idx / K, k = idx - j*K;
  Bp[((size_t)(k>>3)*N + j)*8 + (k&7)] = f2bu(W[idx]);
}

// ---------------- MFMA GEMM: LDS-free, A f32 (cvt in-reg), B pre-packed bf16 ----------------
// 128x128 tile, 256 thr = 4 waves (2m x 2n), wave = 64x64 via 4x4 16x16 frags.
template<int FLAGS>
__global__ __launch_bounds__(256) void k_bgemm(const float* __restrict__ A, const ushort* __restrict__ Bp,
                       const float* __restrict__ bias, const float* __restrict__ resid,
                       float* __restrict__ C, int M, int Nn, int K){
  const int tid = threadIdx.x;
  const int wv = tid>>6, lane = tid&63;
  const int mw = wv>>1, nw = wv&1;
  const int arow = lane&15, ks = lane>>4;
  const int m0 = blockIdx.x*128 + mw*64, n0 = blockIdx.y*128 + nw*64;
  const int kChunk = K / gridDim.z, kBeg = blockIdx.z * kChunk;
  f32x4 acc[4][4] = {};
  const float* Arow0 = A + (size_t)(m0 + 0*16 + arow)*K;
  const float* Arow1 = A + (size_t)(m0 + 1*16 + arow)*K;
  const float* Arow2 = A + (size_t)(m0 + 2*16 + arow)*K;
  const float* Arow3 = A + (size_t)(m0 + 3*16 + arow)*K;
  #pragma unroll 2
  for (int k0 = kBeg; k0 < kBeg+kChunk; k0 += 32){
    const int kb = (k0>>3) + ks;
    bf16x8 af[4];
    {
      const float4* p0 = reinterpret_cast<const float4*>(Arow0 + k0 + ks*8);
      const float4* p1 = reinterpret_cast<const float4*>(Arow1 + k0 + ks*8);
      const float4* p2 = reinterpret_cast<const float4*>(Arow2 + k0 + ks*8);
      const float4* p3 = reinterpret_cast<const float4*>(Arow3 + k0 + ks*8);
      af[0] = cvt8(p0[0], p0[1]);
      af[1] = cvt8(p1[0], p1[1]);
      af[2] = cvt8(p2[0], p2[1]);
      af[3] = cvt8(p3[0], p3[1]);
    }
    #pragma unroll
    for (int nf=0; nf<4; ++nf){
      const int col = n0 + nf*16 + arow;
      bf16x8 bfr = *reinterpret_cast<const bf16x8*>(Bp + ((size_t)kb*Nn + col)*8);
      #pragma unroll
      for (int mf=0; mf<4; ++mf)
        acc[mf][nf] = __builtin_amdgcn_mfma_f32_16x16x32_bf16(af[mf], bfr, acc[mf][nf], 0, 0, 0);
    }
  }
  #pragma unroll
  for (int nf=0; nf<4; ++nf){
    const int n = n0 + nf*16 + arow;
    float bv  = (FLAGS & GF_BIAS)    ? bias[n]  : 0.f;
    float rbv = (FLAGS & GF_RESID_B) ? resid[n] : 0.f;
    #pragma unroll
    for (int mf=0; mf<4; ++mf){
      #pragma unroll
      for (int r=0; r<4; ++r){
        const size_t m = (size_t)m0 + mf*16 + ks*4 + r;
        size_t idx = m*(size_t)Nn + n;
        float v = acc[mf][nf][r];
        if (FLAGS & GF_ATOMIC){ atomicAdd(&C[idx], v); }
        else {
          v += bv;
          if (FLAGS & GF_ADDC)  v += C[idx];
          if (FLAGS & GF_RELU)  v = fmaxf(v, 0.f);
          if (FLAGS & GF_RESID) v += resid[idx];
          v += rbv;
          if (FLAGS & GF_BF16) reinterpret_cast<__hip_bfloat16*>(C)[idx] = __float2bfloat16(v);
          else C[idx] = v;
        }
      }
    }
  }
}

// ---------------- small utilities ----------------
__global__ void k_rowbias(const float* __restrict__ bias, float* __restrict__ C, int Nn, int total){
  int i = blockIdx.x*256 + threadIdx.x;
  if (i < total) C[i] = bias[i % Nn];
}
__global__ void k_qvec(const float* __restrict__ seed, const float* __restrict__ Wq,
                       const float* __restrict__ bq, float* __restrict__ qv){
  __shared__ float s[256];
  int t = threadIdx.x;
  s[t] = seed[t]; __syncthreads();
  float acc = bq[t];
  for (int c = 0; c < 256; ++c) acc += s[c] * Wq[c*256 + t];
  qv[t] = acc;
}
__global__ void k_concat(const float* __restrict__ p1, const float* __restrict__ p2,
                         const float* __restrict__ p3, float* __restrict__ pooled){
  int idx = blockIdx.x*256 + threadIdx.x;
  int b = idx / 768, j = idx % 768;
  float v = (j < 256) ? p1[b*256+j] : (j < 512) ? p2[b*256+j-256] : p3[b*256+j-512];
  pooled[idx] = v;
}

// ---------------- GRU v6: 1 graph/block, 256 blocks, 256 thr (4 waves) ----------------
// gi via 32-step windowed MFMA (Wih amortized); per-step gh via M=1 MFMA (Whh bf16 stream);
// gates per-thread (1 col each), h kept f32 in register, bf16 in LDS for MFMA A.
// LDS: GIw f32[32][768] | gh f32[768] | Xw ushort[32][32*8] (kb-swizzled) | hbf ushort[256]
__global__ __launch_bounds__(256) void k_gru6(const float* __restrict__ X,
                      const ushort* __restrict__ pIh, const ushort* __restrict__ pHh,
                      const float* __restrict__ gbih, const float* __restrict__ gbhh,
                      float* __restrict__ p2){
  extern __shared__ char gsm[];
  float*  GIw = (float*)gsm;                    // 98304 B
  float*  gh  = (float*)(gsm + 98304);          // 3072 B
  ushort* Xw  = (ushort*)(gsm + 101376);        // 16384 B
  ushort* hbf = (ushort*)(gsm + 117760);        // 512 B
  const int g = blockIdx.x;
  const int tid = threadIdx.x;
  const int wv = tid>>6, lane = tid&63;
  const int arow = lane&15, ks = lane>>4;
  const int c = tid;
  const float bir=gbih[c], biz=gbih[256+c], bin=gbih[512+c];
  const float bhr=gbhh[c], bhz=gbhh[256+c], bhn=gbhh[512+c];
  float h_reg = 0.f;
  hbf[c] = 0;
  const int srow = tid>>3, skb0 = (tid&7)*4;    // staging ownership
  for (int w=0; w<16; ++w){
    const int t0 = w*32;
    __syncthreads();                             // prev window's GIw reads done; hbf init visible
    { // stage Xw rows t0..t0+31 (f32 -> bf16, kb xor-swizzle per row)
      const float* xr = X + ((size_t)(g*512 + t0 + srow))*256;
      #pragma unroll
      for (int j=0; j<4; ++j){
        const int kb = skb0 + j;
        float4 a = *reinterpret_cast<const float4*>(xr + kb*8);
        float4 b = *reinterpret_cast<const float4*>(xr + kb*8 + 4);
        union { ushort u[8]; uint4 q; } r;
        r.u[0]=f2bu(a.x); r.u[1]=f2bu(a.y); r.u[2]=f2bu(a.z); r.u[3]=f2bu(a.w);
        r.u[4]=f2bu(b.x); r.u[5]=f2bu(b.y); r.u[6]=f2bu(b.z); r.u[7]=f2bu(b.w);
        *reinterpret_cast<uint4*>(&Xw[((size_t)srow*32 + (kb ^ (srow&7)))*8]) = r.q;
      }
    }
    __syncthreads();
    { // window GEMM: GIw[32][768] = Xw[32][256] @ pIh; wave wv owns cols wv*192..+192
      f32x4 wacc[2][12] = {};
      #pragma unroll
      for (int kt=0; kt<8; ++kt){
        const int kb = kt*4 + ks;
        bf16x8 af0 = *reinterpret_cast<const bf16x8*>(&Xw[((size_t)arow*32      + (kb ^ (arow&7)))*8]);
        bf16x8 af1 = *reinterpret_cast<const bf16x8*>(&Xw[((size_t)(16+arow)*32 + (kb ^ ((16+arow)&7)))*8]);
        #pragma unroll
        for (int nt=0; nt<12; ++nt){
          const int col = wv*192 + nt*16 + arow;
          bf16x8 bfr = *reinterpret_cast<const bf16x8*>(pIh + ((size_t)kb*768 + col)*8);
          wacc[0][nt] = __builtin_amdgcn_mfma_f32_16x16x32_bf16(af0, bfr, wacc[0][nt], 0,0,0);
          wacc[1][nt] = __builtin_amdgcn_mfma_f32_16x16x32_bf16(af1, bfr, wacc[1][nt], 0,0,0);
        }
      }
      #pragma unroll
      for (int mt=0; mt<2; ++mt){
        #pragma unroll
        for (int nt=0; nt<12; ++nt){
          const int jc = wv*192 + nt*16 + arow;
          #pragma unroll
          for (int r=0; r<4; ++r)
            GIw[(size_t)(mt*16 + ks*4 + r)*768 + jc] = wacc[mt][nt][r];
        }
      }
    }
    __syncthreads();                             // GIw ready; hbf stable
    for (int dt=0; dt<32; ++dt){
      // step MFMA: gh[768] = h[256] @ pHh (M=1: only D row 0 read)
      f32x4 sacc[12] = {};
      #pragma unroll
      for (int kt=0; kt<8; ++kt){
        const int kb = kt*4 + ks;
        bf16x8 haf = {};
        if (arow == 0) haf = *reinterpret_cast<const bf16x8*>(&hbf[kb*8]);
        #pragma unroll
        for (int nt=0; nt<12; ++nt){
          const int col = wv*192 + nt*16 + arow;
          bf16x8 bfr = *reinterpret_cast<const bf16x8*>(pHh + ((size_t)kb*768 + col)*8);
          sacc[nt] = __builtin_amdgcn_mfma_f32_16x16x32_bf16(haf, bfr, sacc[nt], 0,0,0);
        }
      }
      if (lane < 16){
        #pragma unroll
        for (int nt=0; nt<12; ++nt) gh[wv*192 + nt*16 + lane] = sacc[nt][0];
      }
      __syncthreads();                           // gh ready
      {
        float ghr = gh[c], ghz = gh[256+c], ghn = gh[512+c];
        const float* gi = GIw + (size_t)dt*768;
        float r = sigm(gi[c]     + bir + ghr + bhr);
        float z = sigm(gi[256+c] + biz + ghz + bhz);
        float n = tanhf(gi[512+c] + bin + r*(ghn + bhn));
        h_reg = (1.f - z)*n + z*h_reg;
        hbf[c] = f2bu(h_reg);
      }
      __syncthreads();                           // hbf ready for next step
    }
  }
  p2[(size_t)g*256 + c] = h_reg;
}

// ---------------- fused SAB attention, bf16 K/V: per (graph-in-chunk, 8 q-rows) ----
__global__ __launch_bounds__(256) void k_attn(float* __restrict__ Q, const __hip_bfloat16* __restrict__ K,
                       const __hip_bfloat16* __restrict__ V){
  __shared__ float Qs[8*256];
  __shared__ float S [8*512];
  __shared__ uint4 Ks[32*32];
  const int g = blockIdx.y, q0 = blockIdx.x*8, tid = threadIdx.x;
  const size_t gb = (size_t)g*512*256;
  for (int i=tid;i<2048;i+=256) Qs[i] = Q[gb + (size_t)q0*256 + i];
  const int q = tid>>5, kl = tid&31;
  const float* qp = Qs + q*256;
  float* Sq = S + q*512;
  for (int kt=0; kt<512; kt+=32){
    __syncthreads();
    for (int i=tid;i<1024;i+=256){
      int row = i>>5, c8 = i&31;
      Ks[row*32 + (c8^row)] =
        reinterpret_cast<const uint4*>(K + gb + (size_t)(kt+row)*256)[c8];
    }
    __syncthreads();
    float d = 0.f;
    #pragma unroll
    for (int c8=0;c8<32;++c8){
      uint4 kv = Ks[kl*32 + (c8^kl)];
      const float* qq = qp + c8*8;
      d += qq[0]*blo(kv.x) + qq[1]*bhi(kv.x) + qq[2]*blo(kv.y) + qq[3]*bhi(kv.y)
         + qq[4]*blo(kv.z) + qq[5]*bhi(kv.z) + qq[6]*blo(kv.w) + qq[7]*bhi(kv.w);
    }
    Sq[kt+kl] = d;
  }
  __syncthreads();
  float m = -3e38f;
  for (int j=kl;j<512;j+=32) m = fmaxf(m, Sq[j]);
  #pragma unroll
  for (int o=1;o<32;o<<=1) m = fmaxf(m, __shfl_xor(m,o));
  float sum = 0.f;
  for (int j=kl;j<512;j+=32){ float e = __expf((Sq[j]-m)*0.0625f); Sq[j]=e; sum+=e; }
  #pragma unroll
  for (int o=1;o<32;o<<=1) sum += __shfl_xor(sum,o);
  const float inv = 1.f/sum;
  __syncthreads();
  const int c0 = kl*8;
  float a0=0,a1=0,a2=0,a3=0,a4=0,a5=0,a6=0,a7=0;
  for (int k=0;k<512;++k){
    float a = Sq[k];
    uint4 vv = *reinterpret_cast<const uint4*>(V + gb + (size_t)k*256 + c0);
    a0+=a*blo(vv.x); a1+=a*bhi(vv.x); a2+=a*blo(vv.y); a3+=a*bhi(vv.y);
    a4+=a*blo(vv.z); a5+=a*bhi(vv.z); a6+=a*blo(vv.w); a7+=a*bhi(vv.w);
  }
  float* op = Q + gb + (size_t)(q0+q)*256 + c0;
  float4 o0 = {a0*inv,a1*inv,a2*inv,a3*inv};
  float4 o1 = {a4*inv,a5*inv,a6*inv,a7*inv};
  *reinterpret_cast<float4*>(op)   = o0;
  *reinterpret_cast<float4*>(op+4) = o1;
}

// ---------------- PMA attention (1 query per graph), chunked ----------------
__global__ __launch_bounds__(256) void k_attn2(const float* __restrict__ K2, const float* __restrict__ V2,
                        const float* __restrict__ qv, float* __restrict__ av2){
  int g = blockIdx.x, tid = threadIdx.x;
  __shared__ float qs[256];
  __shared__ float sc[512];
  __shared__ float red[4];
  qs[tid] = qv[tid];
  __syncthreads();
  const size_t gb = (size_t)g*512*256;
  float l0=0.f, l1=0.f;
  for (int j0=0;j0<2;++j0){
    int j = tid + j0*256;
    const float* kr = K2 + gb + (size_t)j*256;
    float a = 0.f;
    for (int c=0;c<256;c+=4){
      float4 k4 = *reinterpret_cast<const float4*>(kr + c);
      a += k4.x*qs[c] + k4.y*qs[c+1] + k4.z*qs[c+2] + k4.w*qs[c+3];
    }
    a *= 0.0625f;
    if (j0) l1=a; else l0=a;
  }
  float m = fmaxf(l0,l1);
  #pragma unroll
  for (int o=1;o<64;o<<=1) m = fmaxf(m, __shfl_xor(m,o));
  if ((tid&63)==0) red[tid>>6] = m;
  __syncthreads();
  m = fmaxf(fmaxf(red[0],red[1]), fmaxf(red[2],red[3]));
  __syncthreads();
  float e0 = __expf(l0-m), e1 = __expf(l1-m);
  sc[tid]=e0; sc[tid+256]=e1;
  float s = e0+e1;
  #pragma unroll
  for (int o=1;o<64;o<<=1) s += __shfl_xor(s,o);
  if ((tid&63)==0) red[tid>>6] = s;
  __syncthreads();
  s = red[0]+red[1]+red[2]+red[3];
  float invs = 1.f/s;
  float acc = 0.f;
  for (int j=0;j<512;++j) acc += sc[j] * V2[gb + (size_t)j*256 + tid];
  av2[(size_t)g*256+tid] = acc*invs;
}

// =====================================================================
extern "C" void kernel_launch(void* const* d_in, const int* in_sizes, int n_in,
                              void* d_out, int out_size, void* d_ws, size_t ws_size,
                              hipStream_t stream){
  const int*   x      = (const int*)  d_in[0];
  const int*   ei     = (const int*)  d_in[1];
  const float* emb_w  = (const float*)d_in[3];
  const float* c1_lW  = (const float*)d_in[4];
  const float* c1_lb  = (const float*)d_in[5];
  const float* c1_rW  = (const float*)d_in[6];
  const float* t1     = (const float*)d_in[7];
  const float* c2_lW  = (const float*)d_in[8];
  const float* c2_lb  = (const float*)d_in[9];
  const float* c2_rW  = (const float*)d_in[10];
  const float* t2     = (const float*)d_in[11];
  const float* mlp_W  = (const float*)d_in[12];
  const float* mlp_b  = (const float*)d_in[13];
  const float* gWih   = (const float*)d_in[14];
  const float* gWhh   = (const float*)d_in[15];
  const float* gbih   = (const float*)d_in[16];
  const float* gbhh   = (const float*)d_in[17];
  const float* stWq   = (const float*)d_in[18];
  const float* stbq   = (const float*)d_in[19];
  const float* stWk   = (const float*)d_in[20];
  const float* stbk   = (const float*)d_in[21];
  const float* stWv   = (const float*)d_in[22];
  const float* stbv   = (const float*)d_in[23];
  const float* stWo   = (const float*)d_in[24];
  const float* stbo   = (const float*)d_in[25];
  const float* stlW   = (const float*)d_in[26];
  const float* stlb   = (const float*)d_in[27];
  const float* pma_lW = (const float*)d_in[28];
  const float* pma_lb = (const float*)d_in[29];
  const float* seed   = (const float*)d_in[30];
  const float* fin_W  = (const float*)d_in[31];
  const float* fin_b  = (const float*)d_in[32];
  float* out = (float*)d_out;

  // ---- choose chunk size by available workspace ----
  auto needFor = [](int CHe)->size_t{
    size_t bufN = (size_t)CHe*512*256;
    size_t floats = (size_t)33554432 + 3*bufN + 2*524288 + 2*196608 + 8*65536 + 196608 + 320;
    size_t ints   = 131072 + 131200 + 131072 + 262144 + 128 + 128;
    return floats*4 + ints*4 + 4096;
  };
  const int CHe = (ws_size >= needFor(64)) ? 64 : 32;
  if (ws_size < needFor(32)) return;            // diagnostic fail instead of OOB hang
  const int NCHUNKe = BG / CHe;
  const int NCNe = CHe * 512;
  const size_t bufN = (size_t)CHe*512*256;

  // ---- workspace carve ----
  float* H2   = (float*)d_ws;                    // NN*256 f32 (persists)
  float* bufA = H2   + (size_t)33554432;
  float* bufB = bufA + bufN;
  float* bufC = bufB + bufN;
  float* h0   = bufC + bufN;                     // NN*4  (dead after conv phase -> st packs)
  float* ag1  = h0   + (size_t)524288;           // NN*4  (dead after conv phase)
  float* wT1  = ag1  + (size_t)524288;           // GRU packs (pIh/pHh)
  float* wT2  = wT1  + (size_t)196608;           // c2 packs
  float* p1   = wT2  + (size_t)196608;
  float* p2   = p1   + (size_t)65536;
  float* p3   = p2   + (size_t)65536;
  float* av2  = p3   + (size_t)65536;
  float* s1   = av2  + (size_t)65536;
  float* s2v  = s1   + (size_t)65536;
  float* v3   = s2v  + (size_t)65536;
  float* h3   = v3   + (size_t)65536;
  float* pooled = h3 + (size_t)65536;            // 256*768
  float* qv   = pooled + (size_t)196608;         // 256 (+pad)
  int*   deg  = (int*)(qv + 320);
  int*   offs = deg  + 131072;
  int*   cur  = offs + 131200;
  int*   esrc = cur  + 131072;
  int*   bsum = esrc + 262144;
  int*   boff = bsum + 128;

  // packed-weight pointers (overlaid on dead float areas)
  ushort* pIh  = (ushort*)wT1;                   // 196608 ush
  ushort* pHh  = (ushort*)(wT1 + 98304);         // 196608 ush
  ushort* pC2l = (ushort*)wT2;                   // 65536 ush
  ushort* pC2r = (ushort*)(wT2 + 32768);         // 65536 ush
  float*  pa   = h0;                             // 1,048,576 floats available after conv phase
  ushort* pQ0  = (ushort*)(pa);
  ushort* pK0  = (ushort*)(pa + 32768);
  ushort* pV0  = (ushort*)(pa + 65536);
  ushort* pO0  = (ushort*)(pa + 98304);
  ushort* pL0  = (ushort*)(pa + 131072);
  ushort* pPma = (ushort*)(pa + 163840);
  ushort* pK1  = (ushort*)(pa + 196608);
  ushort* pV1  = (ushort*)(pa + 229376);
  ushort* pO1  = (ushort*)(pa + 262144);
  ushort* pL1  = (ushort*)(pa + 294912);
  ushort* pV2  = (ushort*)(pa + 327680);
  ushort* pO2  = (ushort*)(pa + 360448);
  ushort* pL2  = (ushort*)(pa + 393216);
  ushort* pFin = (ushort*)(pa + 425984);         // 589824 ush -> ends at 720896 floats < 1,048,576

  const int ls0 = 65536, ls1 = 256;

  // ---- 1. node encoder ----
  k_node_enc<<<NN/256, 256, 0, stream>>>(x, emb_w, h0);   // h0 used through conv phase

  // ---- 2. CSR ----
  k_zero<<<NN/256, 256, 0, stream>>>(deg, NN);
  k_count<<<NE/256, 256, 0, stream>>>(ei, deg);
  k_blocksum<<<128, 256, 0, stream>>>(deg, bsum);
  k_scanbsum<<<1, 128, 0, stream>>>(bsum, boff, offs + NN);
  k_scanchunk<<<128, 256, 0, stream>>>(deg, boff, offs);
  k_zero<<<NN/256, 256, 0, stream>>>(cur, NN);
  k_fill<<<NE/256, 256, 0, stream>>>(ei, offs, cur, esrc);

  // ---- 3. conv1 aggregation + early packs (c2 / gru areas are free now) ----
  k_aggr4<<<NN/256, 256, 0, stream>>>(h0, offs, esrc, t1, ag1);
  k_packb <<<256, 256, 0, stream>>>(c2_lW, pC2l, 256, 256);
  k_packb <<<256, 256, 0, stream>>>(c2_rW, pC2r, 256, 256);
  k_packbT<<<768, 256, 0, stream>>>(gWih, pIh, 256, 768);
  k_packbT<<<768, 256, 0, stream>>>(gWhh, pHh, 256, 768);

  // ---- 4. conv1 + conv2, chunked ----
  for (int cg = 0; cg < NCHUNKe; ++cg){
    const int base = cg * NCNe;
    float* Hc = H2 + (size_t)base * 256;
    const dim3 gg(NCNe/128, 2, 1);
    k_conv1_lin<<<NCNe, 256, 0, stream>>>(ag1, h0, c1_lW, c1_lb, c1_rW, bufA, base);
    k_aggr256<<<NCNe, 256, 0, stream>>>(bufA, offs, esrc, t2, bufB, base);
    k_bgemm<0><<<gg, 256, 0, stream>>>(bufB, pC2l, nullptr, nullptr, Hc, NCNe, 256, 256);
    k_bgemm<GF_BIAS|GF_ADDC|GF_RELU><<<gg, 256, 0, stream>>>(bufA, pC2r, c2_lb, nullptr, Hc, NCNe, 256, 256);
  }
  // H2 = h2 (full)

  // ---- 5. p1 = MLP pool (M=256, K=131072, split-K atomic, f32 path) ----
  k_rowbias<<<256, 256, 0, stream>>>(mlp_b, p1, 256, 65536);
  k_gemm<GF_ATOMIC><<<dim3(2, 2, 64), 256, 0, stream>>>(H2, mlp_W, nullptr, nullptr, p1, 256, 256, NN);

  // ---- 6. GRU (MFMA M=1 recurrence + windowed Wih; 256 blocks) ----
  k_gru6<<<BG, 256, 118272, stream>>>(H2, pIh, pHh, gbih, gbhh, p2);

  // ---- 7. st packs (h0/ag1 dead now) + set transformer, chunked ----
  k_packb<<<256, 256, 0, stream>>>(stWq,        pQ0, 256, 256);
  k_packb<<<256, 256, 0, stream>>>(stWk,        pK0, 256, 256);
  k_packb<<<256, 256, 0, stream>>>(stWv,        pV0, 256, 256);
  k_packb<<<256, 256, 0, stream>>>(stWo,        pO0, 256, 256);
  k_packb<<<256, 256, 0, stream>>>(stlW,        pL0, 256, 256);
  k_packb<<<256, 256, 0, stream>>>(pma_lW,      pPma,256, 256);
  k_packb<<<256, 256, 0, stream>>>(stWk + ls0,  pK1, 256, 256);
  k_packb<<<256, 256, 0, stream>>>(stWv + ls0,  pV1, 256, 256);
  k_packb<<<256, 256, 0, stream>>>(stWo + ls0,  pO1, 256, 256);
  k_packb<<<256, 256, 0, stream>>>(stlW + ls0,  pL1, 256, 256);
  k_packb<<<256, 256, 0, stream>>>(stWv + 2*ls0,pV2, 256, 256);
  k_packb<<<256, 256, 0, stream>>>(stWo + 2*ls0,pO2, 256, 256);
  k_packb<<<256, 256, 0, stream>>>(stlW + 2*ls0,pL2, 256, 256);
  k_packb<<<2304, 256, 0, stream>>>(fin_W,      pFin,768, 768);
  k_qvec<<<1, 256, 0, stream>>>(seed, stWq + ls0, stbq + ls1, qv);

  for (int cg = 0; cg < NCHUNKe; ++cg){
    const int base = cg * NCNe;
    float* Hc = H2 + (size_t)base * 256;
    const dim3 gg(NCNe/128, 2, 1);
    k_bgemm<GF_BIAS><<<gg, 256, 0, stream>>>(Hc, pQ0, stbq, nullptr, bufA, NCNe, 256, 256);            // Q f32
    k_bgemm<GF_BIAS|GF_BF16><<<gg, 256, 0, stream>>>(Hc, pK0, stbk, nullptr, bufB, NCNe, 256, 256);    // K bf16
    k_bgemm<GF_BIAS|GF_BF16><<<gg, 256, 0, stream>>>(Hc, pV0, stbv, nullptr, bufC, NCNe, 256, 256);    // V bf16
    k_attn<<<dim3(64, CHe), 256, 0, stream>>>(bufA, (const __hip_bfloat16*)bufB, (const __hip_bfloat16*)bufC);
    k_bgemm<GF_BIAS|GF_RESID><<<gg, 256, 0, stream>>>(bufA, pO0, stbo, Hc, Hc, NCNe, 256, 256);        // h_sab in-place
    k_bgemm<GF_BIAS|GF_RELU|GF_RESID><<<gg, 256, 0, stream>>>(Hc, pL0, stlb, Hc, bufA, NCNe, 256, 256);// h_enc
    k_bgemm<GF_BIAS|GF_RELU><<<gg, 256, 0, stream>>>(bufA, pPma, pma_lb, nullptr, bufB, NCNe, 256, 256);// kk
    k_bgemm<GF_BIAS><<<gg, 256, 0, stream>>>(bufB, pK1, stbk + ls1, nullptr, bufA, NCNe, 256, 256);    // K2 f32
    k_bgemm<GF_BIAS><<<gg, 256, 0, stream>>>(bufB, pV1, stbv + ls1, nullptr, bufC, NCNe, 256, 256);    // V2 f32
    k_attn2<<<CHe, 256, 0, stream>>>(bufA, bufC, qv, av2 + (size_t)cg*CHe*256);
  }

  // ---- 8. PMA tail + decoder SAB (small, full batch) ----
  k_bgemm<GF_BIAS|GF_RESID_B><<<dim3(2, 2, 1), 256, 0, stream>>>(av2, pO1, stbo + ls1, seed, s1, 256, 256, 256);
  k_bgemm<GF_BIAS|GF_RELU|GF_RESID><<<dim3(2, 2, 1), 256, 0, stream>>>(s1, pL1, stlb + ls1, s1, s2v, 256, 256, 256);
  k_bgemm<GF_BIAS><<<dim3(2, 2, 1), 256, 0, stream>>>(s2v, pV2, stbv + 2*ls1, nullptr, v3, 256, 256, 256);
  k_bgemm<GF_BIAS|GF_RESID><<<dim3(2, 2, 1), 256, 0, stream>>>(v3, pO2, stbo + 2*ls1, s2v, h3, 256, 256, 256);
  k_bgemm<GF_BIAS|GF_RELU|GF_RESID><<<dim3(2, 2, 1), 256, 0, stream>>>(h3, pL2, stlb + 2*ls1, h3, p3, 256, 256, 256);

  // ---- 9. concat + final linear ----
  k_concat<<<768, 256, 0, stream>>>(p1, p2, p3, pooled);
  k_bgemm<GF_BIAS><<<dim3(2, 6, 1), 256, 0, stream>>>(pooled, pFin, fin_b, nullptr, out, 256, 768, 768);
}